// Round 6
// baseline (135.106 us; speedup 1.0000x reference)
//
#include <hip/hip_runtime.h>

#define HID 256
#define NSEQ 1024
#define NH 16
#define DH 4
#define NB 4
#define SCALEF 0.5f
#define HEADSZ (NB * NH * NSEQ * DH)   // 262144 floats per projection buffer

typedef float f4 __attribute__((ext_vector_type(4)));   // native vec type

// ---------------------------------------------------------------------------
// Kernel 1: 1x1-conv projections, written in the reference's rearranged view:
//   flat c*N+pos == d*(N*H) + n*H + h  =>  d=c>>4, n=(c&15)*64+(pos>>4), h=pos&15
// f4-vectorized global->LDS staging (16B/lane), double-buffered: chunk c+1's
// loads are issued before chunk c's compute so HBM latency hides under FMAs.
// ---------------------------------------------------------------------------
__global__ __launch_bounds__(256) void proj_kernel(
    const float* __restrict__ q, const float* __restrict__ k,
    const float* __restrict__ v, const float* __restrict__ Wq,
    const float* __restrict__ Wk, const float* __restrict__ Wv,
    float* __restrict__ ws)
{
    const int tid   = threadIdx.x;
    const int pos_l = tid & 63;
    int cb = __builtin_amdgcn_readfirstlane(tid >> 6);  // wave-uniform channel grp
    const int p    = blockIdx.y;
    const int b    = blockIdx.z;
    const int pos0 = blockIdx.x * 64;

    const float* in = (p == 0) ? q : (p == 1) ? k : v;
    const float* W  = (p == 0) ? Wq : (p == 1) ? Wk : Wv;
    float* dst = ws + (size_t)p * HEADSZ;

    __shared__ float lds_in[64][64];         // 16 KB input tile

    const int row_l = tid >> 4;              // 0..15
    const int col4  = tid & 15;              // f4 column
    const float* inb = in + (size_t)b * HID * NSEQ + pos0;

    float acc[16];
#pragma unroll
    for (int j = 0; j < 16; ++j) acc[j] = 0.f;

    f4 vbuf[4];
#pragma unroll
    for (int t = 0; t < 4; ++t)
        vbuf[t] = *(const f4*)(inb + (size_t)(row_l + 16 * t) * NSEQ + col4 * 4);

    for (int c = 0; c < 4; ++c) {
#pragma unroll
        for (int t = 0; t < 4; ++t)
            *(f4*)&lds_in[row_l + 16 * t][col4 * 4] = vbuf[t];
        __syncthreads();
        if (c < 3) {
#pragma unroll
            for (int t = 0; t < 4; ++t)
                vbuf[t] = *(const f4*)(inb +
                    (size_t)((c + 1) * 64 + row_l + 16 * t) * NSEQ + col4 * 4);
        }
#pragma unroll
        for (int i8 = 0; i8 < 64; i8 += 8) {
            float x[8];
#pragma unroll
            for (int j = 0; j < 8; ++j) x[j] = lds_in[i8 + j][pos_l];
#pragma unroll
            for (int kk = 0; kk < 16; ++kk) {
                const float* wr = W + (cb * 16 + kk) * HID + c * 64 + i8;
#pragma unroll
                for (int j = 0; j < 8; ++j)
                    acc[kk] = fmaf(wr[j], x[j], acc[kk]);
            }
        }
        __syncthreads();
    }

    const int pos_g = pos0 + pos_l;
    const int h     = pos_g & 15;
    const int nsub  = pos_g >> 4;
#pragma unroll
    for (int kk = 0; kk < 16; ++kk) {
        int c = cb * 16 + kk;
        int d = c >> 4;
        int n = (c & 15) * 64 + nsub;
        dst[(((size_t)b * NH + h) * NSEQ + n) * DH + d] = acc[kk];
    }
}

// ---------------------------------------------------------------------------
// Kernel 2: attention. 4 waves/block; wave owns 16 queries x 1024 keys.
// Lane = (qg:2b, kg:4b) -> 4 query rows x one f4-of-keys. Bias stream is
// DOUBLE-BUFFERED: round m0+64's 4 NT loads are issued before round m0's
// compute, so the HBM stream never stalls the wave. K/V f4 loads are
// L1/L2-resident. Fixed-max softmax (M=16), final reduce = 4 shfl_xor steps.
// min-waves=3 (VGPR cap ~170, ~120 live) -> no forced spill.
// ---------------------------------------------------------------------------
__global__ __launch_bounds__(256, 3) void attn_kernel(
    const float* __restrict__ bias, const float* __restrict__ ws,
    float* __restrict__ x2)
{
    const int tid  = threadIdx.x;
    const int lane = tid & 63;
    const int wave = tid >> 6;
    const int qg   = lane >> 4;      // 0..3
    const int kg   = lane & 15;      // 0..15
    const int h    = blockIdx.y;
    const int b    = blockIdx.z;
    const int n0   = blockIdx.x * 64 + wave * 16;

    const float4* Qh = (const float4*)(ws);
    const float4* Kh = (const float4*)(ws + (size_t)1 * HEADSZ);
    const float4* Vh = (const float4*)(ws + (size_t)2 * HEADSZ);
    const int headbase = (b * NH + h) * NSEQ;

    float4 q4[4];
#pragma unroll
    for (int r = 0; r < 4; ++r) q4[r] = Qh[headbase + n0 + qg * 4 + r];

    float sum[4];
    float o[4][4];
#pragma unroll
    for (int r = 0; r < 4; ++r) {
        sum[r] = 0.f;
#pragma unroll
        for (int d = 0; d < 4; ++d) o[r][d] = 0.f;
    }

    const float* bbase =
        bias + ((size_t)headbase + n0 + qg * 4) * NSEQ + kg * 4;
    const int kvbase = headbase + kg * 4;

#define LOG2E 1.44269504f
#define EOFF  (-16.f * LOG2E)

    f4 bb[4], bbn[4];
#pragma unroll
    for (int r = 0; r < 4; ++r)
        bb[r] = __builtin_nontemporal_load((const f4*)(bbase + (size_t)r * NSEQ));

    for (int m0 = 0; m0 < NSEQ; m0 += 64) {
        if (m0 + 64 < NSEQ) {
#pragma unroll
            for (int r = 0; r < 4; ++r)
                bbn[r] = __builtin_nontemporal_load(
                    (const f4*)(bbase + (size_t)r * NSEQ + m0 + 64));
        }
        float4 kb[4], vb[4];
#pragma unroll
        for (int i = 0; i < 4; ++i) {
            kb[i] = Kh[kvbase + m0 + i];
            vb[i] = Vh[kvbase + m0 + i];
        }
#pragma unroll
        for (int r = 0; r < 4; ++r) {
            const float be[4] = {bb[r].x, bb[r].y, bb[r].z, bb[r].w};
#pragma unroll
            for (int i = 0; i < 4; ++i) {
                float dot = q4[r].x * kb[i].x + q4[r].y * kb[i].y +
                            q4[r].z * kb[i].z + q4[r].w * kb[i].w;
                float s = fmaf(dot, SCALEF, be[i]);
                float e = exp2f(fmaf(s, LOG2E, EOFF));   // exp(s-16)
                sum[r] += e;
                o[r][0] = fmaf(e, vb[i].x, o[r][0]);
                o[r][1] = fmaf(e, vb[i].y, o[r][1]);
                o[r][2] = fmaf(e, vb[i].z, o[r][2]);
                o[r][3] = fmaf(e, vb[i].w, o[r][3]);
            }
        }
#pragma unroll
        for (int r = 0; r < 4; ++r) bb[r] = bbn[r];
    }

    // reduce over kg (lane bits 0..3): 4 butterfly steps
#pragma unroll
    for (int st = 1; st <= 8; st <<= 1) {
#pragma unroll
        for (int r = 0; r < 4; ++r) {
            sum[r]  += __shfl_xor(sum[r],  st, 64);
            o[r][0] += __shfl_xor(o[r][0], st, 64);
            o[r][1] += __shfl_xor(o[r][1], st, 64);
            o[r][2] += __shfl_xor(o[r][2], st, 64);
            o[r][3] += __shfl_xor(o[r][3], st, 64);
        }
    }

    if (kg < 4) {
        float4 wv;
        wv.x = o[0][kg] / sum[0];
        wv.y = o[1][kg] / sum[1];
        wv.z = o[2][kg] / sum[2];
        wv.w = o[3][kg] / sum[3];
        *(float4*)(x2 + ((size_t)b * (NH * DH) + h * DH + kg) * NSEQ
                      + n0 + qg * 4) = wv;
    }
}

// ---------------------------------------------------------------------------
// Kernel 3: output 1x1 conv + BN(eval) + LeakyReLU. f4-vectorized: each
// thread owns 4 positions x 4 output channels. 256 blocks.
// ---------------------------------------------------------------------------
__global__ __launch_bounds__(256) void out_kernel(
    const float* __restrict__ x2, const float* __restrict__ Wo,
    const float* __restrict__ bo, const float* __restrict__ gamma,
    const float* __restrict__ beta, const float* __restrict__ rmean,
    const float* __restrict__ rvar, float* __restrict__ out)
{
    const int pos4 = threadIdx.x * 4;
    const int o0   = blockIdx.y * 4;
    const int b    = blockIdx.z;

    const float* xb = x2 + (size_t)b * (NH * DH) * NSEQ;

    f4 acc[4];
#pragma unroll
    for (int j = 0; j < 4; ++j) acc[j] = (f4)(0.f);

#pragma unroll 8
    for (int c = 0; c < NH * DH; ++c) {
        f4 x = *(const f4*)(xb + (size_t)c * NSEQ + pos4);
#pragma unroll
        for (int j = 0; j < 4; ++j)
            acc[j] += Wo[(o0 + j) * (NH * DH) + c] * x;
    }
#pragma unroll
    for (int j = 0; j < 4; ++j) {
        int oc = o0 + j;
        float scale = gamma[oc] * rsqrtf(rvar[oc] + 1e-5f);
        f4 y = (acc[j] + (bo[oc] - rmean[oc])) * scale + beta[oc];
        float* dst = out + ((size_t)b * HID + oc) * NSEQ + pos4;
        f4 res;
#pragma unroll
        for (int d = 0; d < 4; ++d) {
            float yy = y[d];
            res[d] = (yy > 0.f) ? yy : 0.2f * yy;
        }
        *(f4*)dst = res;
    }
}

extern "C" void kernel_launch(void* const* d_in, const int* in_sizes, int n_in,
                              void* d_out, int out_size, void* d_ws, size_t ws_size,
                              hipStream_t stream) {
    const float* q     = (const float*)d_in[0];
    const float* k     = (const float*)d_in[1];
    const float* v     = (const float*)d_in[2];
    const float* bias  = (const float*)d_in[3];
    const float* Wq    = (const float*)d_in[4];
    const float* Wk    = (const float*)d_in[5];
    const float* Wv    = (const float*)d_in[6];
    const float* Wo    = (const float*)d_in[7];
    const float* bo    = (const float*)d_in[8];
    const float* gamma = (const float*)d_in[9];
    const float* beta  = (const float*)d_in[10];
    const float* rmean = (const float*)d_in[11];
    const float* rvar  = (const float*)d_in[12];

    float* ws = (float*)d_ws;                 // 3 proj buffers + X2 = 4 MB
    float* x2 = ws + (size_t)3 * HEADSZ;
    float* out = (float*)d_out;

    proj_kernel<<<dim3(NSEQ / 64, 3, NB), 256, 0, stream>>>(q, k, v, Wq, Wk, Wv, ws);
    attn_kernel<<<dim3(NSEQ / 64, NH, NB), 256, 0, stream>>>(bias, ws, x2);
    out_kernel<<<dim3(1, HID / 4, NB), 256, 0, stream>>>(
        x2, Wo, bo, gamma, beta, rmean, rvar, out);
}